// Round 1
// 651.728 us; speedup vs baseline: 1.0425x; 1.0425x over previous
//
#include <hip/hip_runtime.h>
#include <hip/hip_bf16.h>

#define E      100
#define E2     112
#define NSLOT  20
#define BB     512
#define TT     1005
#define NFULL  100
#define LL     10
#define REST   5
#define VV     32000

typedef _Float16 f16x8 __attribute__((ext_vector_type(8)));
typedef _Float16 f16x4 __attribute__((ext_vector_type(4)));
typedef float    f32x16 __attribute__((ext_vector_type(16)));

// ---------------------------------------------------------------------------
// k_cvt: R_w -> R16 [32000][112] f16 (K-padded), and Wm16 [128][112] f16
// (rows 0..99 = W_w, 100..119 = w_mem, 120..127 = 0).
// ---------------------------------------------------------------------------
__global__ __launch_bounds__(256) void k_cvt(
    const float* __restrict__ R_w, const float* __restrict__ W_w,
    const float* __restrict__ w_mem,
    _Float16* __restrict__ R16, _Float16* __restrict__ Wm16)
{
    const int gid = blockIdx.x * 256 + threadIdx.x;   // 3500*256 = 896000 exact
    {
        int v = gid / 28, e4 = gid % 28;
        f16x4 o;
        if (e4 < 25) {
            float4 x = *(const float4*)&R_w[(size_t)v * E + e4 * 4];
            o[0] = (_Float16)x.x; o[1] = (_Float16)x.y;
            o[2] = (_Float16)x.z; o[3] = (_Float16)x.w;
        } else { o[0] = o[1] = o[2] = o[3] = (_Float16)0.f; }
        *(f16x4*)&R16[(size_t)v * E2 + e4 * 4] = o;
    }
    if (gid < 128 * 28) {
        int j = gid / 28, e4 = gid % 28;
        f16x4 o; o[0] = o[1] = o[2] = o[3] = (_Float16)0.f;
        if (e4 < 25 && j < 120) {
            float4 x = (j < 100) ? *(const float4*)&W_w[j * E + e4 * 4]
                                 : *(const float4*)&w_mem[(j - 100) * E + e4 * 4];
            o[0] = (_Float16)x.x; o[1] = (_Float16)x.y;
            o[2] = (_Float16)x.z; o[3] = (_Float16)x.w;
        }
        *(f16x4*)&Wm16[j * E2 + e4 * 4] = o;
    }
}

// ---------------------------------------------------------------------------
// k_prep: streaming. s16[(n*512+b)*112 + e] = sum_l f[l][e]*x[b][10n+l][e],
// e>=100 zero-padded. q_all fp32. No barriers in the hot loop.
// ---------------------------------------------------------------------------
__global__ __launch_bounds__(256, 2) void k_prep(
    const float* __restrict__ in_data, const float* __restrict__ f,
    _Float16* __restrict__ s16, float* __restrict__ q_all)
{
    __shared__ float4 f4s[250];
    const int tid = threadIdx.x;
    const int b   = blockIdx.x;
    if (tid < 250) f4s[tid] = ((const float4*)f)[tid];
    __syncthreads();

    const size_t base = (size_t)b * TT * E;
    for (int idx = tid; idx < 2500; idx += 256) {
        int n = idx / 25, e4 = idx - n * 25;
        float4 a; a.x = a.y = a.z = a.w = 0.f;
        const float* xp = in_data + base + (size_t)(n * LL) * E + e4 * 4;
        #pragma unroll
        for (int l = 0; l < LL; ++l) {
            float4 x = *(const float4*)(xp + l * E);
            float4 fv = f4s[l * 25 + e4];
            a.x += fv.x * x.x; a.y += fv.y * x.y;
            a.z += fv.z * x.z; a.w += fv.w * x.w;
        }
        f16x4 o;
        o[0] = (_Float16)a.x; o[1] = (_Float16)a.y;
        o[2] = (_Float16)a.z; o[3] = (_Float16)a.w;
        *(f16x4*)&s16[((size_t)n * BB + b) * E2 + e4 * 4] = o;
    }
    // zero-pad e=100..111 for all 100 rows of this b
    for (int idx = tid; idx < 600; idx += 256) {
        int n = idx / 6, k = idx - n * 6;
        ((unsigned int*)s16)[(((size_t)n * BB + b) * E2 + 100) / 2 + k] = 0u;
    }
    if (tid < E) {
        const float* fp = (const float*)f4s;
        float a = 0.f;
        #pragma unroll
        for (int l = 0; l < REST; ++l)
            a += fp[l * E + tid] * in_data[base + (size_t)(NFULL * LL + l) * E + tid];
        q_all[(size_t)b * E + tid] = a;
    }
}

// ---------------------------------------------------------------------------
// k_mm: sws16[row][j] = s16[row][:] @ Wm16[j][:]  (row = t*512+b, j<128)
// M=51200, N=128, K=112. f16 MFMA, frag-major LDS staging.
// ---------------------------------------------------------------------------
__global__ __launch_bounds__(256, 2) void k_mm(
    const _Float16* __restrict__ s16, const _Float16* __restrict__ Wm16,
    _Float16* __restrict__ sws16)
{
    __shared__ __align__(16) _Float16 AF[14 * 128 * 8];
    __shared__ __align__(16) _Float16 BF[14 * 128 * 8];
    const int tid  = threadIdx.x;
    const int mb   = blockIdx.x;
    const int lane = tid & 63;
    const int wv   = tid >> 6;
    const int half = lane >> 5;
    const int jt   = wv * 32 + (lane & 31);

    for (int idx = tid; idx < 128 * 14; idx += 256) {
        int m = idx / 14, c8 = idx - m * 14;
        *(f16x8*)&AF[(c8 * 128 + m) * 8] =
            *(const f16x8*)&s16[((size_t)mb * 128 + m) * E2 + c8 * 8];
        *(f16x8*)&BF[(c8 * 128 + m) * 8] =
            *(const f16x8*)&Wm16[m * E2 + c8 * 8];
    }
    __syncthreads();

    f16x8 Bfr[7];
    #pragma unroll
    for (int ck = 0; ck < 7; ++ck)
        Bfr[ck] = *(const f16x8*)&BF[((ck * 2 + half) * 128 + jt) * 8];

    #pragma unroll
    for (int Mt = 0; Mt < 4; ++Mt) {
        f32x16 acc;
        #pragma unroll
        for (int r = 0; r < 16; ++r) acc[r] = 0.f;
        #pragma unroll
        for (int ck = 0; ck < 7; ++ck) {
            f16x8 a = *(const f16x8*)&AF[((ck * 2 + half) * 128 + 32 * Mt + (lane & 31)) * 8];
            acc = __builtin_amdgcn_mfma_f32_32x32x16_f16(a, Bfr[ck], acc, 0, 0, 0);
        }
        #pragma unroll
        for (int r = 0; r < 16; ++r) {
            int row = 32 * Mt + (r & 3) + 8 * (r >> 2) + 4 * half;
            sws16[((size_t)mb * 128 + row) * 128 + jt] = (_Float16)acc[r];
        }
    }
}

// ---------------------------------------------------------------------------
// k_scan v2: 2 barriers/step, MFMA-computed gate+norm.
//  - gate dot  Σ_e R[n,e]·s[e]  rides the main U-MFMA in padding column 100
//    (the two fcol==100 threads refresh their B-frag from svL each step).
//  - norm      Σ_e R[n,e]^2     = diag of Gram(R) — wave 0 runs 7 extra MFMAs
//    with hA as both operands (f16^2 exact in f32: same precision as before).
//  - d8 partial buffer + wave-0 reduce + barrier B2 deleted; g/rn recomputed
//    redundantly per thread from broadcast LDS reads (trans pipe).
//  - all r-loops fully unrolled with compile-time indices (no scratch).
//  - barriers are lgkmcnt-only (no vmcnt drain) so the 2B/lane prefetch of
//    s16/sws16 stays in flight across the whole step.
// ---------------------------------------------------------------------------
#define BAR() do { asm volatile("s_waitcnt lgkmcnt(0)" ::: "memory"); \
                   __builtin_amdgcn_s_barrier(); } while (0)

__global__ __launch_bounds__(256, 2) void k_scan(
    const float* __restrict__ h0, const float* __restrict__ w_mem,
    const float* __restrict__ U_w, const float* __restrict__ V_w,
    const float* __restrict__ a_dm,
    const _Float16* __restrict__ s16, const _Float16* __restrict__ sws16,
    float* __restrict__ h_final)
{
    __shared__ __align__(16) _Float16 h16f[7 * 64 * 8];      // A-frags of R
    __shared__ __align__(16) _Float16 svL[2][128];
    __shared__ __align__(16) _Float16 swsL[2][128];
    __shared__ __align__(16) float    npL[32];               // |R[n]|^2 (Gram diag)
    __shared__ __align__(16) float    grawL[32];             // R[n]·s   (MFMA col 100)

    const int tid  = threadIdx.x;
    const int b    = blockIdx.x;
    const int lane = tid & 63;
    const int wv   = tid >> 6;
    const int col  = lane & 31;
    const int half = lane >> 5;
    const int fcol = wv * 32 + col;
    const int nval = half ? 8 : 12;      // valid r count (rows<20)
    const float adm = a_dm[0];

    // ---- one-time setup ----
    f16x8 Bf[7];                         // U^T B-frags (col 100 becomes s_t)
    #pragma unroll
    for (int ck = 0; ck < 7; ++ck) {
        #pragma unroll
        for (int j = 0; j < 8; ++j) {
            int e = 16 * ck + 8 * half + j;
            Bf[ck][j] = (_Float16)((fcol < E && e < E) ? U_w[fcol * E + e] : 0.f);
        }
    }
    float VwC[16], hC[16];
    #pragma unroll
    for (int r = 0; r < 16; ++r) { VwC[r] = 0.f; hC[r] = 0.f; }
    for (int e4 = 0; e4 < 25; ++e4) {
        float4 v4 = make_float4(0.f, 0.f, 0.f, 0.f);
        if (fcol < E) v4 = *(const float4*)&V_w[fcol * E + e4 * 4];
        #pragma unroll
        for (int r = 0; r < 16; ++r) {
            if (r < nval) {
                int row = (r & 3) + 8 * (r >> 2) + 4 * half;
                float4 w4 = *(const float4*)&w_mem[row * E + e4 * 4];
                VwC[r] += w4.x * v4.x + w4.y * v4.y + w4.z * v4.z + w4.w * v4.w;
            }
        }
    }
    #pragma unroll
    for (int r = 0; r < 16; ++r) {
        if (r < nval) {
            int row = (r & 3) + 8 * (r >> 2) + 4 * half;
            if (fcol < E) hC[r] = h0[row * E + fcol];
        }
    }
    // initial pack of R_0 = h0 into A-frags; rows 20..31 and pad cols zeroed
    #pragma unroll
    for (int r = 0; r < 16; ++r) {
        int row = (r & 3) + 8 * (r >> 2) + 4 * half;
        if (fcol < E2) {
            int slot = (fcol >> 4) * 64 + ((fcol >> 3) & 1) * 32 + row;
            h16f[slot * 8 + (fcol & 7)] = (_Float16)((r < nval) ? hC[r] : 0.f);
        }
    }
    // t=0 sv/sws
    if (tid < E2) svL[0][tid] = s16[(size_t)b * E2 + tid];
    else if (tid >= 128) swsL[0][tid - 128] = sws16[(size_t)b * 128 + (tid - 128)];
    BAR();

    const unsigned short* s16u   = (const unsigned short*)s16;
    const unsigned short* sws16u = (const unsigned short*)sws16;

    for (int t = 0; t < NFULL; ++t) {
        const int p = t & 1;

        // ---- phase A: prefetch, frags, MFMAs, np/graw publication ----
        unsigned short nsv = 0, nsw = 0;
        if (t + 1 < NFULL) {
            if (tid < E2) nsv = s16u[((size_t)(t + 1) * BB + b) * E2 + tid];
            else if (tid >= 128) nsw = sws16u[((size_t)(t + 1) * BB + b) * 128 + (tid - 128)];
        }
        if (fcol == 100) {               // inject s_t into B column 100
            #pragma unroll
            for (int ck = 0; ck < 7; ++ck)
                Bf[ck] = *(const f16x8*)&svL[p][16 * ck + 8 * half];
        }
        f16x8 hA[7];
        #pragma unroll
        for (int ck = 0; ck < 7; ++ck)
            hA[ck] = *(const f16x8*)&h16f[(ck * 64 + lane) * 8];

        f32x16 acc;
        #pragma unroll
        for (int r = 0; r < 16; ++r) acc[r] = 0.f;
        #pragma unroll
        for (int ck = 0; ck < 7; ++ck)
            acc = __builtin_amdgcn_mfma_f32_32x32x16_f16(hA[ck], Bf[ck], acc, 0, 0, 0);

        if (wv == 0) {                   // Gram(R): diag = |R[n]|^2
            f32x16 acc2;
            #pragma unroll
            for (int r = 0; r < 16; ++r) acc2[r] = 0.f;
            #pragma unroll
            for (int ck = 0; ck < 7; ++ck)
                acc2 = __builtin_amdgcn_mfma_f32_32x32x16_f16(hA[ck], hA[ck], acc2, 0, 0, 0);
            #pragma unroll
            for (int r = 0; r < 16; ++r) {
                int row = (r & 3) + 8 * (r >> 2) + 4 * half;
                if (row < NSLOT && row == col) npL[row] = acc2[r];
            }
        }
        if (fcol == 100) {               // gate raw dot from MFMA column 100
            #pragma unroll
            for (int r = 0; r < 16; ++r) {
                int row = (r & 3) + 8 * (r >> 2) + 4 * half;
                if (row < NSLOT) grawL[row] = acc[r];
            }
        }
        BAR();                                                // B1

        // ---- phase B: per-row g/rn (redundant), epilogue, pack, commit ----
        const float swf = (fcol < E) ? (float)swsL[p][fcol] : 0.f;
        #pragma unroll
        for (int r = 0; r < 16; ++r) {
            if (r < nval) {
                int row = (r & 3) + 8 * (r >> 2) + 4 * half;
                float rn = (t == 0) ? 1.f : rsqrtf(npL[row]);
                float d  = fmaf(rn, grawL[row], (float)swsL[p][100 + row]);
                float g  = 1.f / (1.f + __expf(-d));
                float c  = fmaf(rn, acc[r], VwC[r] + swf);
                c = (c >= 0.f) ? c : adm * c;
                float hnew = fmaf(rn, hC[r], g * c);
                hC[r] = hnew;
                if (fcol < E) {
                    int slot = (fcol >> 4) * 64 + ((fcol >> 3) & 1) * 32 + row;
                    h16f[slot * 8 + (fcol & 7)] = (_Float16)hnew;
                }
            }
        }
        if (t + 1 < NFULL) {
            int pn = p ^ 1;
            if (tid < E2) ((unsigned short*)svL[pn])[tid] = nsv;
            else if (tid >= 128) ((unsigned short*)swsL[pn])[tid - 128] = nsw;
        }
        BAR();                                                // B2
    }

    // ---- final normalization of R_100 (Gram diag on wave 0) ----
    {
        if (wv == 0) {
            f16x8 hA[7];
            #pragma unroll
            for (int ck = 0; ck < 7; ++ck)
                hA[ck] = *(const f16x8*)&h16f[(ck * 64 + lane) * 8];
            f32x16 acc2;
            #pragma unroll
            for (int r = 0; r < 16; ++r) acc2[r] = 0.f;
            #pragma unroll
            for (int ck = 0; ck < 7; ++ck)
                acc2 = __builtin_amdgcn_mfma_f32_32x32x16_f16(hA[ck], hA[ck], acc2, 0, 0, 0);
            #pragma unroll
            for (int r = 0; r < 16; ++r) {
                int row = (r & 3) + 8 * (r >> 2) + 4 * half;
                if (row < NSLOT && row == col) npL[row] = acc2[r];
            }
        }
        BAR();
        if (fcol < E) {
            #pragma unroll
            for (int r = 0; r < 16; ++r) {
                if (r < nval) {
                    int row = (r & 3) + 8 * (r >> 2) + 4 * half;
                    h_final[(size_t)b * NSLOT * E + row * E + fcol] = rsqrtf(npL[row]) * hC[r];
                }
            }
        }
    }
}

// ---------------------------------------------------------------------------
// k_attn: scores->softmax->u->y->prelu->py16 (padded to 112). One block per b.
// ---------------------------------------------------------------------------
__global__ __launch_bounds__(256, 2) void k_attn(
    const float* __restrict__ h_final, const float* __restrict__ q_all,
    const float* __restrict__ H_w, const float* __restrict__ H_b,
    const float* __restrict__ a_out, _Float16* __restrict__ py16)
{
    __shared__ float Hl[E * 101];
    __shared__ float h_l[NSLOT * E];
    __shared__ float q_l[E], u_l[E];
    __shared__ float part[200], party[200];
    __shared__ float dl[NSLOT], pl[NSLOT];
    const int tid = threadIdx.x;
    const int b   = blockIdx.x;

    for (int idx = tid; idx < E * E; idx += 256) {
        int fr = idx / E, e = idx - fr * E;
        Hl[fr * 101 + e] = H_w[idx];
    }
    for (int idx = tid; idx < NSLOT * E; idx += 256)
        h_l[idx] = h_final[(size_t)b * NSLOT * E + idx];
    if (tid < E) q_l[tid] = q_all[(size_t)b * E + tid];
    __syncthreads();

    if (tid < 200) {
        int n = tid / 10, j = tid - n * 10;
        float a = 0.f;
        #pragma unroll
        for (int k = 0; k < 10; ++k) { int e = j * 10 + k; a += h_l[n * E + e] * q_l[e]; }
        part[tid] = a;
    }
    __syncthreads();
    if (tid < NSLOT) {
        float d = 0.f;
        #pragma unroll
        for (int j = 0; j < 10; ++j) d += part[tid * 10 + j];
        dl[tid] = d;
    }
    __syncthreads();
    if (tid < NSLOT) {
        float m = -1e30f;
        for (int i = 0; i < NSLOT; ++i) m = fmaxf(m, dl[i]);
        float s = 0.f;
        for (int i = 0; i < NSLOT; ++i) s += __expf(dl[i] - m);
        pl[tid] = __expf(dl[tid] - m) / s;
    }
    __syncthreads();
    if (tid < E) {
        float u = 0.f;
        for (int n = 0; n < NSLOT; ++n) u += pl[n] * h_l[n * E + tid];
        u_l[tid] = u;
    }
    __syncthreads();
    if (tid < 200) {
        int fr = tid % E, hf = tid / E;
        float a = 0.f;
        for (int e = hf * 50; e < hf * 50 + 50; ++e) a += u_l[e] * Hl[fr * 101 + e];
        party[tid] = a;
    }
    __syncthreads();
    if (tid < E2) {
        if (tid < E) {
            float y = q_l[tid] + H_b[tid] + party[tid] + party[100 + tid];
            const float ao = a_out[0];
            y = (y >= 0.f) ? y : ao * y;
            py16[(size_t)b * E2 + tid] = (_Float16)y;
        } else py16[(size_t)b * E2 + tid] = (_Float16)0.f;
    }
}

// ---------------------------------------------------------------------------
// k_out: out = py @ R^T + R_b via f16 MFMA. Tiles 128(b) x 128(v), K=112.
// ---------------------------------------------------------------------------
__global__ __launch_bounds__(256, 2) void k_out(
    const _Float16* __restrict__ py16, const _Float16* __restrict__ R16,
    const float* __restrict__ R_b, float* __restrict__ out)
{
    __shared__ __align__(16) _Float16 AF[14 * 128 * 8];
    __shared__ __align__(16) _Float16 BF[14 * 128 * 8];
    const int tid  = threadIdx.x;
    const int vb   = blockIdx.x;          // 250
    const int mb   = blockIdx.y;          // 4
    const int lane = tid & 63;
    const int wv   = tid >> 6;
    const int half = lane >> 5;
    const int jt   = wv * 32 + (lane & 31);
    const int v0   = vb * 128;

    for (int idx = tid; idx < 128 * 14; idx += 256) {
        int m = idx / 14, c8 = idx - m * 14;
        *(f16x8*)&AF[(c8 * 128 + m) * 8] =
            *(const f16x8*)&py16[((size_t)mb * 128 + m) * E2 + c8 * 8];
        *(f16x8*)&BF[(c8 * 128 + m) * 8] =
            *(const f16x8*)&R16[(size_t)(v0 + m) * E2 + c8 * 8];
    }
    __syncthreads();

    f16x8 Bfr[7];
    #pragma unroll
    for (int ck = 0; ck < 7; ++ck)
        Bfr[ck] = *(const f16x8*)&BF[((ck * 2 + half) * 128 + jt) * 8];
    const float rbv = R_b[v0 + jt];

    #pragma unroll
    for (int Mt = 0; Mt < 4; ++Mt) {
        f32x16 acc;
        #pragma unroll
        for (int r = 0; r < 16; ++r) acc[r] = 0.f;
        #pragma unroll
        for (int ck = 0; ck < 7; ++ck) {
            f16x8 a = *(const f16x8*)&AF[((ck * 2 + half) * 128 + 32 * Mt + (lane & 31)) * 8];
            acc = __builtin_amdgcn_mfma_f32_32x32x16_f16(a, Bfr[ck], acc, 0, 0, 0);
        }
        #pragma unroll
        for (int r = 0; r < 16; ++r) {
            int row = 32 * Mt + (r & 3) + 8 * (r >> 2) + 4 * half;
            out[((size_t)mb * 128 + row) * VV + v0 + jt] = acc[r] + rbv;
        }
    }
}

// ---------------------------------------------------------------------------
extern "C" void kernel_launch(void* const* d_in, const int* in_sizes, int n_in,
                              void* d_out, int out_size, void* d_ws, size_t ws_size,
                              hipStream_t stream)
{
    const float* in_data = (const float*)d_in[0];
    const float* f       = (const float*)d_in[1];
    const float* h0      = (const float*)d_in[2];
    const float* w_mem   = (const float*)d_in[3];
    const float* U_w     = (const float*)d_in[4];
    const float* V_w     = (const float*)d_in[5];
    const float* W_w     = (const float*)d_in[6];
    const float* a_dm    = (const float*)d_in[7];
    const float* H_w     = (const float*)d_in[8];
    const float* H_b     = (const float*)d_in[9];
    const float* R_w     = (const float*)d_in[10];
    const float* R_b     = (const float*)d_in[11];
    const float* a_out   = (const float*)d_in[12];
    float* out = (float*)d_out;

    char* ws = (char*)d_ws;
    _Float16* s16    = (_Float16*)(ws);                       // 11,468,800 B
    _Float16* sws16  = (_Float16*)(ws + 11468800);            // 13,107,200 B
    _Float16* R16    = (_Float16*)(ws + 24576000);            //  7,168,000 B
    _Float16* Wm16   = (_Float16*)(ws + 31744000);            //     28,672 B
    float*    q_all  = (float*)   (ws + 31772672);            //    204,800 B
    float*    h_fin  = (float*)   (ws + 31977472);            //  4,096,000 B
    _Float16* py16   = (_Float16*)(ws + 36073472);            //    114,688 B

    k_cvt <<<3500, 256, 0, stream>>>(R_w, W_w, w_mem, R16, Wm16);
    k_prep<<<BB, 256, 0, stream>>>(in_data, f, s16, q_all);
    k_mm  <<<400, 256, 0, stream>>>(s16, Wm16, sws16);
    k_scan<<<BB, 256, 0, stream>>>(h0, w_mem, U_w, V_w, a_dm, s16, sws16, h_fin);
    k_attn<<<BB, 256, 0, stream>>>(h_fin, q_all, H_w, H_b, a_out, py16);
    k_out <<<dim3(VV / 128, 4), 256, 0, stream>>>(py16, R16, R_b, out);
}

// Round 2
// 561.222 us; speedup vs baseline: 1.2106x; 1.1613x over previous
//
#include <hip/hip_runtime.h>
#include <hip/hip_bf16.h>

#define E      100
#define E2     112
#define NSLOT  20
#define BB     512
#define TT     1005
#define NFULL  100
#define LL     10
#define REST   5
#define VV     32000

typedef _Float16 f16x8 __attribute__((ext_vector_type(8)));
typedef _Float16 f16x4 __attribute__((ext_vector_type(4)));
typedef float    f32x16 __attribute__((ext_vector_type(16)));

// ---------------------------------------------------------------------------
// k_cvt: R_w -> R16 [32000][112] f16 (K-padded), and Wm16 [128][112] f16
// (rows 0..99 = W_w, 100..119 = w_mem, 120..127 = 0).
// ---------------------------------------------------------------------------
__global__ __launch_bounds__(256) void k_cvt(
    const float* __restrict__ R_w, const float* __restrict__ W_w,
    const float* __restrict__ w_mem,
    _Float16* __restrict__ R16, _Float16* __restrict__ Wm16)
{
    const int gid = blockIdx.x * 256 + threadIdx.x;   // 3500*256 = 896000 exact
    {
        int v = gid / 28, e4 = gid % 28;
        f16x4 o;
        if (e4 < 25) {
            float4 x = *(const float4*)&R_w[(size_t)v * E + e4 * 4];
            o[0] = (_Float16)x.x; o[1] = (_Float16)x.y;
            o[2] = (_Float16)x.z; o[3] = (_Float16)x.w;
        } else { o[0] = o[1] = o[2] = o[3] = (_Float16)0.f; }
        *(f16x4*)&R16[(size_t)v * E2 + e4 * 4] = o;
    }
    if (gid < 128 * 28) {
        int j = gid / 28, e4 = gid % 28;
        f16x4 o; o[0] = o[1] = o[2] = o[3] = (_Float16)0.f;
        if (e4 < 25 && j < 120) {
            float4 x = (j < 100) ? *(const float4*)&W_w[j * E + e4 * 4]
                                 : *(const float4*)&w_mem[(j - 100) * E + e4 * 4];
            o[0] = (_Float16)x.x; o[1] = (_Float16)x.y;
            o[2] = (_Float16)x.z; o[3] = (_Float16)x.w;
        }
        *(f16x4*)&Wm16[j * E2 + e4 * 4] = o;
    }
}

// ---------------------------------------------------------------------------
// k_prep: streaming. s16[(n*512+b)*112 + e] = sum_l f[l][e]*x[b][10n+l][e],
// e>=100 zero-padded. q_all fp32. No barriers in the hot loop.
// ---------------------------------------------------------------------------
__global__ __launch_bounds__(256, 2) void k_prep(
    const float* __restrict__ in_data, const float* __restrict__ f,
    _Float16* __restrict__ s16, float* __restrict__ q_all)
{
    __shared__ float4 f4s[250];
    const int tid = threadIdx.x;
    const int b   = blockIdx.x;
    if (tid < 250) f4s[tid] = ((const float4*)f)[tid];
    __syncthreads();

    const size_t base = (size_t)b * TT * E;
    for (int idx = tid; idx < 2500; idx += 256) {
        int n = idx / 25, e4 = idx - n * 25;
        float4 a; a.x = a.y = a.z = a.w = 0.f;
        const float* xp = in_data + base + (size_t)(n * LL) * E + e4 * 4;
        #pragma unroll
        for (int l = 0; l < LL; ++l) {
            float4 x = *(const float4*)(xp + l * E);
            float4 fv = f4s[l * 25 + e4];
            a.x += fv.x * x.x; a.y += fv.y * x.y;
            a.z += fv.z * x.z; a.w += fv.w * x.w;
        }
        f16x4 o;
        o[0] = (_Float16)a.x; o[1] = (_Float16)a.y;
        o[2] = (_Float16)a.z; o[3] = (_Float16)a.w;
        *(f16x4*)&s16[((size_t)n * BB + b) * E2 + e4 * 4] = o;
    }
    // zero-pad e=100..111 for all 100 rows of this b
    for (int idx = tid; idx < 600; idx += 256) {
        int n = idx / 6, k = idx - n * 6;
        ((unsigned int*)s16)[(((size_t)n * BB + b) * E2 + 100) / 2 + k] = 0u;
    }
    if (tid < E) {
        const float* fp = (const float*)f4s;
        float a = 0.f;
        #pragma unroll
        for (int l = 0; l < REST; ++l)
            a += fp[l * E + tid] * in_data[base + (size_t)(NFULL * LL + l) * E + tid];
        q_all[(size_t)b * E + tid] = a;
    }
}

// ---------------------------------------------------------------------------
// k_mm: sws16[row][j] = s16[row][:] @ Wm16[j][:]  (row = t*512+b, j<128)
// M=51200, N=128, K=112. f16 MFMA, frag-major LDS staging.
// ---------------------------------------------------------------------------
__global__ __launch_bounds__(256, 2) void k_mm(
    const _Float16* __restrict__ s16, const _Float16* __restrict__ Wm16,
    _Float16* __restrict__ sws16)
{
    __shared__ __align__(16) _Float16 AF[14 * 128 * 8];
    __shared__ __align__(16) _Float16 BF[14 * 128 * 8];
    const int tid  = threadIdx.x;
    const int mb   = blockIdx.x;
    const int lane = tid & 63;
    const int wv   = tid >> 6;
    const int half = lane >> 5;
    const int jt   = wv * 32 + (lane & 31);

    for (int idx = tid; idx < 128 * 14; idx += 256) {
        int m = idx / 14, c8 = idx - m * 14;
        *(f16x8*)&AF[(c8 * 128 + m) * 8] =
            *(const f16x8*)&s16[((size_t)mb * 128 + m) * E2 + c8 * 8];
        *(f16x8*)&BF[(c8 * 128 + m) * 8] =
            *(const f16x8*)&Wm16[m * E2 + c8 * 8];
    }
    __syncthreads();

    f16x8 Bfr[7];
    #pragma unroll
    for (int ck = 0; ck < 7; ++ck)
        Bfr[ck] = *(const f16x8*)&BF[((ck * 2 + half) * 128 + jt) * 8];

    #pragma unroll
    for (int Mt = 0; Mt < 4; ++Mt) {
        f32x16 acc;
        #pragma unroll
        for (int r = 0; r < 16; ++r) acc[r] = 0.f;
        #pragma unroll
        for (int ck = 0; ck < 7; ++ck) {
            f16x8 a = *(const f16x8*)&AF[((ck * 2 + half) * 128 + 32 * Mt + (lane & 31)) * 8];
            acc = __builtin_amdgcn_mfma_f32_32x32x16_f16(a, Bfr[ck], acc, 0, 0, 0);
        }
        #pragma unroll
        for (int r = 0; r < 16; ++r) {
            int row = 32 * Mt + (r & 3) + 8 * (r >> 2) + 4 * half;
            sws16[((size_t)mb * 128 + row) * 128 + jt] = (_Float16)acc[r];
        }
    }
}

// ---------------------------------------------------------------------------
// k_scan v3: VALU-lean phase B.
//  - per-row (rn, g) computed ONCE per wave (lane n owns row n) with
//    single-inst v_rsq / v_exp / v_rcp; distributed via 2 ds_bpermute per r.
//  - unrolls trimmed 16 -> 12 (dead iterations removed).
//  - h16f XOR-swizzled (byte ^= ((byte>>9)&3)<<5): pack ds_write_b16 goes
//    8-way -> 2-way bank conflict; frag reads remain conflict-free (same
//    pure address transform on both sides; buffer zero-filled once so the
//    pad rows/cols read as zero).
//  - Gram MFMA on wave 1 (wave 3 reloads Bf col 100), publishes to nggL.x;
//    gate raw dot rides main MFMA padding col 100 -> nggL.y.
// ---------------------------------------------------------------------------
#define BAR() do { asm volatile("s_waitcnt lgkmcnt(0)" ::: "memory"); \
                   __builtin_amdgcn_s_barrier(); } while (0)

__device__ __forceinline__ f16x8 h_load(const _Float16* h16f, int ck, int lane) {
    int byte = ck * 1024 + lane * 16;
    byte ^= ((byte >> 9) & 3) << 5;
    return *(const f16x8*)((const char*)h16f + byte);
}

__global__ __launch_bounds__(256, 2) void k_scan(
    const float* __restrict__ h0, const float* __restrict__ w_mem,
    const float* __restrict__ U_w, const float* __restrict__ V_w,
    const float* __restrict__ a_dm,
    const _Float16* __restrict__ s16, const _Float16* __restrict__ sws16,
    float* __restrict__ h_final)
{
    __shared__ __align__(16) _Float16 h16f[7 * 64 * 8];      // A-frags of R (swizzled)
    __shared__ __align__(16) _Float16 svL[2][128];
    __shared__ __align__(16) _Float16 swsL[2][128];
    __shared__ __align__(16) float2   nggL[32];              // .x=|R[n]|^2  .y=R[n]·s

    const int tid  = threadIdx.x;
    const int b    = blockIdx.x;
    const int lane = tid & 63;
    const int wv   = tid >> 6;
    const int col  = lane & 31;
    const int half = lane >> 5;
    const int fcol = wv * 32 + col;
    const float adm = a_dm[0];

    // per-thread h16f write base (swizzle key constant per thread)
    const int hkey = ((fcol >> 3) & 3) << 5;
    const int hbase = (fcol >> 3) * 512 + (fcol & 7) * 2 + 64 * half;

    // ---- one-time setup ----
    f16x8 Bf[7];                         // U^T B-frags (col 100 becomes s_t)
    #pragma unroll
    for (int ck = 0; ck < 7; ++ck) {
        #pragma unroll
        for (int j = 0; j < 8; ++j) {
            int e = 16 * ck + 8 * half + j;
            Bf[ck][j] = (_Float16)((fcol < E && e < E) ? U_w[fcol * E + e] : 0.f);
        }
    }
    float VwC[12], hC[12];
    #pragma unroll
    for (int r = 0; r < 12; ++r) { VwC[r] = 0.f; hC[r] = 0.f; }
    for (int e4 = 0; e4 < 25; ++e4) {
        float4 v4 = make_float4(0.f, 0.f, 0.f, 0.f);
        if (fcol < E) v4 = *(const float4*)&V_w[fcol * E + e4 * 4];
        #pragma unroll
        for (int r = 0; r < 12; ++r) {
            if (r < 8 || half == 0) {
                int row = (r & 3) + 8 * (r >> 2) + 4 * half;
                float4 w4 = *(const float4*)&w_mem[row * E + e4 * 4];
                VwC[r] += w4.x * v4.x + w4.y * v4.y + w4.z * v4.z + w4.w * v4.w;
            }
        }
    }
    #pragma unroll
    for (int r = 0; r < 12; ++r) {
        if (r < 8 || half == 0) {
            int row = (r & 3) + 8 * (r >> 2) + 4 * half;
            if (fcol < E) hC[r] = h0[row * E + fcol];
        }
    }
    // zero-fill h16f (covers pad rows 20..31 and cols 100..111 in swizzled space)
    for (int idx = tid; idx < 896; idx += 256)
        ((float2*)h16f)[idx] = make_float2(0.f, 0.f);
    __syncthreads();
    // pack R_0 = h0 into swizzled A-frags
    #pragma unroll
    for (int r = 0; r < 12; ++r) {
        if (r < 8 || half == 0) {
            if (fcol < E) {
                const int rc = (r & 3) + 8 * (r >> 2);
                int byte = (hbase + rc * 16) ^ hkey;
                *(_Float16*)((char*)h16f + byte) = (_Float16)hC[r];
            }
        }
    }
    // t=0 sv/sws
    if (tid < E2) svL[0][tid] = s16[(size_t)b * E2 + tid];
    else if (tid >= 128) swsL[0][tid - 128] = sws16[(size_t)b * 128 + (tid - 128)];
    BAR();

    const unsigned short* s16u   = (const unsigned short*)s16;
    const unsigned short* sws16u = (const unsigned short*)sws16;

    for (int t = 0; t < NFULL; ++t) {
        const int p = t & 1;

        // ---- phase A: prefetch, frags, MFMAs, ngg publication ----
        unsigned short nsv = 0, nsw = 0;
        if (t + 1 < NFULL) {
            if (tid < E2) nsv = s16u[((size_t)(t + 1) * BB + b) * E2 + tid];
            else if (tid >= 128) nsw = sws16u[((size_t)(t + 1) * BB + b) * 128 + (tid - 128)];
        }
        if (fcol == 100) {               // inject s_t into B column 100
            #pragma unroll
            for (int ck = 0; ck < 7; ++ck)
                Bf[ck] = *(const f16x8*)&svL[p][16 * ck + 8 * half];
        }
        f16x8 hA[7];
        #pragma unroll
        for (int ck = 0; ck < 7; ++ck)
            hA[ck] = h_load(h16f, ck, lane);

        f32x16 acc;
        #pragma unroll
        for (int r = 0; r < 16; ++r) acc[r] = 0.f;
        #pragma unroll
        for (int ck = 0; ck < 7; ++ck)
            acc = __builtin_amdgcn_mfma_f32_32x32x16_f16(hA[ck], Bf[ck], acc, 0, 0, 0);

        if (wv == 1) {                   // Gram(R): diag = |R[n]|^2
            f32x16 acc2;
            #pragma unroll
            for (int r = 0; r < 16; ++r) acc2[r] = 0.f;
            #pragma unroll
            for (int ck = 0; ck < 7; ++ck)
                acc2 = __builtin_amdgcn_mfma_f32_32x32x16_f16(hA[ck], hA[ck], acc2, 0, 0, 0);
            #pragma unroll
            for (int r = 0; r < 12; ++r) {
                if (r < 8 || half == 0) {
                    int row = (r & 3) + 8 * (r >> 2) + 4 * half;
                    if (row == col) nggL[row].x = acc2[r];
                }
            }
        }
        if (fcol == 100) {               // gate raw dot from MFMA column 100
            #pragma unroll
            for (int r = 0; r < 12; ++r) {
                if (r < 8 || half == 0) {
                    int row = (r & 3) + 8 * (r >> 2) + 4 * half;
                    nggL[row].y = acc[r];
                }
            }
        }
        BAR();                                                // B1

        // ---- phase B: wave-wide per-row scalars, bpermute, epilogue ----
        const float swf = (fcol < E) ? (float)swsL[p][fcol] : 0.f;
        const int rw = (col < NSLOT) ? col : (NSLOT - 1);
        float2 ng = nggL[rw];
        float rn_l = (t == 0) ? 1.f : __builtin_amdgcn_rsqf(ng.x);
        float d_l  = fmaf(rn_l, ng.y, (float)swsL[p][100 + rw]);
        float g_l  = __builtin_amdgcn_rcpf(1.f + __expf(-d_l));

        #pragma unroll
        for (int r = 0; r < 12; ++r) {
            if (r < 8 || half == 0) {
                const int rc = (r & 3) + 8 * (r >> 2);
                int bpi = rc * 4 + half * 16;
                float rn = __int_as_float(__builtin_amdgcn_ds_bpermute(bpi, __float_as_int(rn_l)));
                float g  = __int_as_float(__builtin_amdgcn_ds_bpermute(bpi, __float_as_int(g_l)));
                float c  = fmaf(rn, acc[r], VwC[r] + swf);
                c = (c >= 0.f) ? c : adm * c;
                float hnew = fmaf(rn, hC[r], g * c);
                hC[r] = hnew;
                if (fcol < E) {
                    int byte = (hbase + rc * 16) ^ hkey;
                    *(_Float16*)((char*)h16f + byte) = (_Float16)hnew;
                }
            }
        }
        if (t + 1 < NFULL) {
            int pn = p ^ 1;
            if (tid < E2) ((unsigned short*)svL[pn])[tid] = nsv;
            else if (tid >= 128) ((unsigned short*)swsL[pn])[tid - 128] = nsw;
        }
        BAR();                                                // B2
    }

    // ---- final normalization of R_100 (Gram diag on wave 1) ----
    {
        if (wv == 1) {
            f16x8 hA[7];
            #pragma unroll
            for (int ck = 0; ck < 7; ++ck)
                hA[ck] = h_load(h16f, ck, lane);
            f32x16 acc2;
            #pragma unroll
            for (int r = 0; r < 16; ++r) acc2[r] = 0.f;
            #pragma unroll
            for (int ck = 0; ck < 7; ++ck)
                acc2 = __builtin_amdgcn_mfma_f32_32x32x16_f16(hA[ck], hA[ck], acc2, 0, 0, 0);
            #pragma unroll
            for (int r = 0; r < 12; ++r) {
                if (r < 8 || half == 0) {
                    int row = (r & 3) + 8 * (r >> 2) + 4 * half;
                    if (row == col) nggL[row].x = acc2[r];
                }
            }
        }
        BAR();
        if (fcol < E) {
            #pragma unroll
            for (int r = 0; r < 12; ++r) {
                if (r < 8 || half == 0) {
                    int row = (r & 3) + 8 * (r >> 2) + 4 * half;
                    h_final[(size_t)b * NSLOT * E + row * E + fcol] =
                        __builtin_amdgcn_rsqf(nggL[row].x) * hC[r];
                }
            }
        }
    }
}

// ---------------------------------------------------------------------------
// k_attn: scores->softmax->u->y->prelu->py16 (padded to 112). One block per b.
// ---------------------------------------------------------------------------
__global__ __launch_bounds__(256, 2) void k_attn(
    const float* __restrict__ h_final, const float* __restrict__ q_all,
    const float* __restrict__ H_w, const float* __restrict__ H_b,
    const float* __restrict__ a_out, _Float16* __restrict__ py16)
{
    __shared__ float Hl[E * 101];
    __shared__ float h_l[NSLOT * E];
    __shared__ float q_l[E], u_l[E];
    __shared__ float part[200], party[200];
    __shared__ float dl[NSLOT], pl[NSLOT];
    const int tid = threadIdx.x;
    const int b   = blockIdx.x;

    for (int idx = tid; idx < E * E; idx += 256) {
        int fr = idx / E, e = idx - fr * E;
        Hl[fr * 101 + e] = H_w[idx];
    }
    for (int idx = tid; idx < NSLOT * E; idx += 256)
        h_l[idx] = h_final[(size_t)b * NSLOT * E + idx];
    if (tid < E) q_l[tid] = q_all[(size_t)b * E + tid];
    __syncthreads();

    if (tid < 200) {
        int n = tid / 10, j = tid - n * 10;
        float a = 0.f;
        #pragma unroll
        for (int k = 0; k < 10; ++k) { int e = j * 10 + k; a += h_l[n * E + e] * q_l[e]; }
        part[tid] = a;
    }
    __syncthreads();
    if (tid < NSLOT) {
        float d = 0.f;
        #pragma unroll
        for (int j = 0; j < 10; ++j) d += part[tid * 10 + j];
        dl[tid] = d;
    }
    __syncthreads();
    if (tid < NSLOT) {
        float m = -1e30f;
        for (int i = 0; i < NSLOT; ++i) m = fmaxf(m, dl[i]);
        float s = 0.f;
        for (int i = 0; i < NSLOT; ++i) s += __expf(dl[i] - m);
        pl[tid] = __expf(dl[tid] - m) / s;
    }
    __syncthreads();
    if (tid < E) {
        float u = 0.f;
        for (int n = 0; n < NSLOT; ++n) u += pl[n] * h_l[n * E + tid];
        u_l[tid] = u;
    }
    __syncthreads();
    if (tid < 200) {
        int fr = tid % E, hf = tid / E;
        float a = 0.f;
        for (int e = hf * 50; e < hf * 50 + 50; ++e) a += u_l[e] * Hl[fr * 101 + e];
        party[tid] = a;
    }
    __syncthreads();
    if (tid < E2) {
        if (tid < E) {
            float y = q_l[tid] + H_b[tid] + party[tid] + party[100 + tid];
            const float ao = a_out[0];
            y = (y >= 0.f) ? y : ao * y;
            py16[(size_t)b * E2 + tid] = (_Float16)y;
        } else py16[(size_t)b * E2 + tid] = (_Float16)0.f;
    }
}

// ---------------------------------------------------------------------------
// k_out: out = py @ R^T + R_b via f16 MFMA. Tiles 128(b) x 128(v), K=112.
// ---------------------------------------------------------------------------
__global__ __launch_bounds__(256, 2) void k_out(
    const _Float16* __restrict__ py16, const _Float16* __restrict__ R16,
    const float* __restrict__ R_b, float* __restrict__ out)
{
    __shared__ __align__(16) _Float16 AF[14 * 128 * 8];
    __shared__ __align__(16) _Float16 BF[14 * 128 * 8];
    const int tid  = threadIdx.x;
    const int vb   = blockIdx.x;          // 250
    const int mb   = blockIdx.y;          // 4
    const int lane = tid & 63;
    const int wv   = tid >> 6;
    const int half = lane >> 5;
    const int jt   = wv * 32 + (lane & 31);
    const int v0   = vb * 128;

    for (int idx = tid; idx < 128 * 14; idx += 256) {
        int m = idx / 14, c8 = idx - m * 14;
        *(f16x8*)&AF[(c8 * 128 + m) * 8] =
            *(const f16x8*)&py16[((size_t)mb * 128 + m) * E2 + c8 * 8];
        *(f16x8*)&BF[(c8 * 128 + m) * 8] =
            *(const f16x8*)&R16[(size_t)(v0 + m) * E2 + c8 * 8];
    }
    __syncthreads();

    f16x8 Bfr[7];
    #pragma unroll
    for (int ck = 0; ck < 7; ++ck)
        Bfr[ck] = *(const f16x8*)&BF[((ck * 2 + half) * 128 + jt) * 8];
    const float rbv = R_b[v0 + jt];

    #pragma unroll
    for (int Mt = 0; Mt < 4; ++Mt) {
        f32x16 acc;
        #pragma unroll
        for (int r = 0; r < 16; ++r) acc[r] = 0.f;
        #pragma unroll
        for (int ck = 0; ck < 7; ++ck) {
            f16x8 a = *(const f16x8*)&AF[((ck * 2 + half) * 128 + 32 * Mt + (lane & 31)) * 8];
            acc = __builtin_amdgcn_mfma_f32_32x32x16_f16(a, Bfr[ck], acc, 0, 0, 0);
        }
        #pragma unroll
        for (int r = 0; r < 16; ++r) {
            int row = 32 * Mt + (r & 3) + 8 * (r >> 2) + 4 * half;
            out[((size_t)mb * 128 + row) * VV + v0 + jt] = acc[r] + rbv;
        }
    }
}

// ---------------------------------------------------------------------------
extern "C" void kernel_launch(void* const* d_in, const int* in_sizes, int n_in,
                              void* d_out, int out_size, void* d_ws, size_t ws_size,
                              hipStream_t stream)
{
    const float* in_data = (const float*)d_in[0];
    const float* f       = (const float*)d_in[1];
    const float* h0      = (const float*)d_in[2];
    const float* w_mem   = (const float*)d_in[3];
    const float* U_w     = (const float*)d_in[4];
    const float* V_w     = (const float*)d_in[5];
    const float* W_w     = (const float*)d_in[6];
    const float* a_dm    = (const float*)d_in[7];
    const float* H_w     = (const float*)d_in[8];
    const float* H_b     = (const float*)d_in[9];
    const float* R_w     = (const float*)d_in[10];
    const float* R_b     = (const float*)d_in[11];
    const float* a_out   = (const float*)d_in[12];
    float* out = (float*)d_out;

    char* ws = (char*)d_ws;
    _Float16* s16    = (_Float16*)(ws);                       // 11,468,800 B
    _Float16* sws16  = (_Float16*)(ws + 11468800);            // 13,107,200 B
    _Float16* R16    = (_Float16*)(ws + 24576000);            //  7,168,000 B
    _Float16* Wm16   = (_Float16*)(ws + 31744000);            //     28,672 B
    float*    q_all  = (float*)   (ws + 31772672);            //    204,800 B
    float*    h_fin  = (float*)   (ws + 31977472);            //  4,096,000 B
    _Float16* py16   = (_Float16*)(ws + 36073472);            //    114,688 B

    k_cvt <<<3500, 256, 0, stream>>>(R_w, W_w, w_mem, R16, Wm16);
    k_prep<<<BB, 256, 0, stream>>>(in_data, f, s16, q_all);
    k_mm  <<<400, 256, 0, stream>>>(s16, Wm16, sws16);
    k_scan<<<BB, 256, 0, stream>>>(h0, w_mem, U_w, V_w, a_dm, s16, sws16, h_fin);
    k_attn<<<BB, 256, 0, stream>>>(h_fin, q_all, H_w, H_b, a_out, py16);
    k_out <<<dim3(VV / 128, 4), 256, 0, stream>>>(py16, R16, R_b, out);
}